// Round 1
// baseline (444.348 us; speedup 1.0000x reference)
//
#include <hip/hip_runtime.h>

// Problem constants (B,C,H,W) = (32,256,32,32), N = H*W = 1024.
constexpr int Bn = 32;
constexpr int Cn = 256;
constexpr int Nn = 1024;

// ---------------------------------------------------------------------------
// Kernel 1: a[b,n] = <x[b,n,:], w1> + b1 ; k[b,n] = <x[b,n,:], w2> + b2
// x[b,n,c] = h[b,c,n]  (h layout [B,C,N], n contiguous -> coalesced across lanes)
// ---------------------------------------------------------------------------
__global__ __launch_bounds__(256) void proj_kernel(
    const float* __restrict__ h,
    const float* __restrict__ w1, const float* __restrict__ w1b,
    const float* __restrict__ w2, const float* __restrict__ w2b,
    float* __restrict__ a_out, float* __restrict__ k_out)
{
    int t = blockIdx.x * 256 + threadIdx.x;   // 0 .. B*N-1
    int b = t >> 10;
    int n = t & (Nn - 1);
    const float* hb = h + (size_t)b * Cn * Nn + n;
    float a1 = 0.f, a2 = 0.f;
#pragma unroll 8
    for (int c = 0; c < Cn; ++c) {
        float v = hb[(size_t)c * Nn];          // lanes: consecutive n -> coalesced
        a1 = fmaf(v, w1[c], a1);               // w1[c] wave-uniform -> s_load
        a2 = fmaf(v, w2[c], a2);
    }
    a_out[t] = a1 + w1b[0];
    k_out[t] = a2 + w2b[0];
}

// ---------------------------------------------------------------------------
// Kernel 2: per block: one batch b, one 64-row i-tile.
//   ctx'[i,c] = sum_n e_in * x[n,c],  S_i = sum_n e_in  (accumulated in-reg)
//   out[b,c,i] = leaky(ctx'/S)
// 128 threads (2 waves). Per-thread tile: 8 rows x 16 cols (4 clusters of 4).
// K-tile = 32: xs[32][260] staged from global, est[32][68] generated on the fly.
// ---------------------------------------------------------------------------
constexpr int KT = 32;
constexpr int XSP = 260;   // pad: read addrs (4*(kt+cg))%32 -> 2-way (free)
constexpr int ESP = 68;    // pad: 272B rows keep b128 alignment, gen writes 2-way

__global__ __launch_bounds__(128, 1) void ctx_kernel(
    const float* __restrict__ h,
    const float* __restrict__ a_g, const float* __restrict__ k_g,
    float* __restrict__ out)
{
    // XCD-aware swizzle: all 16 i-tiles of a batch land on one XCD (%8 heuristic)
    // -> x[b] (1MB) stays L2-resident, 4 batches/XCD = 4MB = L2.
    int vb   = blockIdx.x;        // 0..511
    int xcd  = vb & 7;
    int slot = vb >> 3;           // 0..63
    int b    = xcd * 4 + (slot >> 4);
    int i0   = (slot & 15) * 64;

    __shared__ float xs[KT][XSP];
    __shared__ float est[KT][ESP];
    __shared__ float ks[Nn];
    __shared__ float as[64];
    __shared__ float Sp[2][64];

    const int t     = threadIdx.x;
    const int rg    = t >> 4;        // 0..7  -> rows rg*8 .. rg*8+7
    const int cg    = t & 15;        // cols cg*4 + q*64 + j
    const int row_g = t & 63;        // e-generation row
    const int half  = t >> 6;        // e-generation k-half (wave-uniform)
    const int rg8   = rg * 8;
    const int cg4   = cg * 4;

    const float* hb = h + (size_t)b * Cn * Nn;

    for (int i = t; i < Nn; i += 128) ks[i] = k_g[b * Nn + i];
    if (t < 64) as[t] = a_g[b * Nn + i0 + t];
    __syncthreads();

    float acc[8][16];
#pragma unroll
    for (int r = 0; r < 8; ++r)
#pragma unroll
        for (int c = 0; c < 16; ++c) acc[r][c] = 0.f;
    float Spart = 0.f;
    const float av = as[row_g];

    for (int n0 = 0; n0 < Nn; n0 += KT) {
        __syncthreads();   // previous tile fully consumed
        // ---- stage X tile: x[n0+kt][c] = h[b][c][n0+kt] ----
        {
            int kt4 = (t & 7) << 2;            // 0,4,..,28
            int cb  = t >> 3;                  // 0..15
            const float* src = hb + n0 + kt4;
#pragma unroll
            for (int pass = 0; pass < 16; ++pass) {
                int c = pass * 16 + cb;
                float4 v = *(const float4*)(src + (size_t)c * Nn);
                xs[kt4 + 0][c] = v.x;
                xs[kt4 + 1][c] = v.y;
                xs[kt4 + 2][c] = v.z;
                xs[kt4 + 3][c] = v.w;
            }
        }
        // ---- generate E tile: e = exp(tanh(a_i + k_n)), each value once ----
#pragma unroll
        for (int j = 0; j < 16; ++j) {
            int kt  = (half << 4) + j;         // wave-uniform
            float s = av + ks[n0 + kt];
            float z  = __expf(2.f * s);
            float th = 1.f - 2.f * __builtin_amdgcn_rcpf(z + 1.f);
            float e  = __expf(th);
            est[kt][row_g] = e;
            Spart += e;
        }
        __syncthreads();
        // ---- 8x16 outer-product accumulate ----
#pragma unroll 4
        for (int kt = 0; kt < KT; ++kt) {
            float4 e0 = *(const float4*)&est[kt][rg8];
            float4 e1 = *(const float4*)&est[kt][rg8 + 4];
            float4 x0 = *(const float4*)&xs[kt][cg4];
            float4 x1 = *(const float4*)&xs[kt][cg4 + 64];
            float4 x2 = *(const float4*)&xs[kt][cg4 + 128];
            float4 x3 = *(const float4*)&xs[kt][cg4 + 192];
            float ev[8]  = {e0.x, e0.y, e0.z, e0.w, e1.x, e1.y, e1.z, e1.w};
            float xv[16] = {x0.x, x0.y, x0.z, x0.w, x1.x, x1.y, x1.z, x1.w,
                            x2.x, x2.y, x2.z, x2.w, x3.x, x3.y, x3.z, x3.w};
#pragma unroll
            for (int r = 0; r < 8; ++r)
#pragma unroll
                for (int c = 0; c < 16; ++c)
                    acc[r][c] = fmaf(ev[r], xv[c], acc[r][c]);
        }
    }

    // ---- row-sum reduction (2 partials per row) ----
    Sp[half][row_g] = Spart;
    __syncthreads();

    // ---- epilogue: normalize, LeakyReLU(0.2), write out[b][c][i0+row] ----
    float* ob = out + (size_t)b * Cn * Nn + i0;
#pragma unroll
    for (int r = 0; r < 8; ++r) {
        int row = rg8 + r;
        float inv = __builtin_amdgcn_rcpf(Sp[0][row] + Sp[1][row]);
#pragma unroll
        for (int q = 0; q < 4; ++q)
#pragma unroll
            for (int j = 0; j < 4; ++j) {
                int c = cg4 + q * 64 + j;
                float v = acc[r][q * 4 + j] * inv;
                v = (v >= 0.f) ? v : 0.2f * v;
                ob[(size_t)c * Nn + row] = v;
            }
    }
}

// ---------------------------------------------------------------------------
extern "C" void kernel_launch(void* const* d_in, const int* in_sizes, int n_in,
                              void* d_out, int out_size, void* d_ws, size_t ws_size,
                              hipStream_t stream) {
    const float* h   = (const float*)d_in[0];
    const float* w1w = (const float*)d_in[1];
    const float* w1b = (const float*)d_in[2];
    const float* w2w = (const float*)d_in[3];
    const float* w2b = (const float*)d_in[4];
    float* out = (float*)d_out;

    // workspace: a[B*N], k[B*N]  (256 KB)
    float* a_ws = (float*)d_ws;
    float* k_ws = a_ws + Bn * Nn;

    proj_kernel<<<(Bn * Nn) / 256, 256, 0, stream>>>(h, w1w, w1b, w2w, w2b, a_ws, k_ws);
    ctx_kernel<<<Bn * 16, 128, 0, stream>>>(h, a_ws, k_ws, out);
}

// Round 2
// 158.099 us; speedup vs baseline: 2.8106x; 2.8106x over previous
//
#include <hip/hip_runtime.h>

constexpr int Bn = 32;
constexpr int Cn = 256;
constexpr int Nn = 1024;

constexpr float C2 = 2.8853900817779268f;  // 2/ln2
constexpr float K1 = 1.4426950408889634f;  // 1/ln2

typedef __bf16 v8bf  __attribute__((ext_vector_type(8)));
typedef float  v16f  __attribute__((ext_vector_type(16)));

// ---------------------------------------------------------------------------
// Kernel 1: pa[b,n] = exp2(C2*(<x,w1>+b1)), q[b,n] = exp2(C2*(<x,w2>+b2))
// block = (b, 64-n chunk), 256 threads; wave cq handles c in [cq*64, cq*64+64)
// ---------------------------------------------------------------------------
__global__ __launch_bounds__(256) void proj_kernel(
    const float* __restrict__ h,
    const float* __restrict__ w1, const float* __restrict__ w1b,
    const float* __restrict__ w2, const float* __restrict__ w2b,
    float* __restrict__ pa_g, float* __restrict__ q_g)
{
    int blk = blockIdx.x;            // 512 blocks
    int b   = blk >> 4;
    int n0  = (blk & 15) * 64;
    int t   = threadIdx.x;
    int cq  = t >> 6;                // wave id 0..3 -> c quarter
    int l   = t & 63;
    const float* hb = h + (size_t)b * Cn * Nn + n0 + l;
    float s1 = 0.f, s2 = 0.f;
#pragma unroll 8
    for (int ci = 0; ci < 64; ++ci) {
        int c = cq * 64 + ci;
        float v = hb[(size_t)c * Nn];        // lanes: consecutive n -> coalesced
        s1 = fmaf(v, w1[c], s1);
        s2 = fmaf(v, w2[c], s2);
    }
    __shared__ float p1[4][64], p2[4][64];
    p1[cq][l] = s1;
    p2[cq][l] = s2;
    __syncthreads();
    if (t < 64) {
        float a = p1[0][t] + p1[1][t] + p1[2][t] + p1[3][t] + w1b[0];
        float k = p2[0][t] + p2[1][t] + p2[2][t] + p2[3][t] + w2b[0];
        pa_g[b * Nn + n0 + t] = exp2f(C2 * a);
        q_g [b * Nn + n0 + t] = exp2f(C2 * k);
    }
}

// ---------------------------------------------------------------------------
// Kernel 2: per block: batch b, 128-row i-tile, all 256 c, full K=1024.
// 512 threads = 8 waves. Waves 0-3: rows wm*32, n in [0,512); waves 4-7: same
// rows, n in [512,1024). E generated in registers in A-frag layout; X staged
// h->bf16 LDS in B-frag layout ([c][k], k-contiguous). mfma_f32_32x32x16_bf16.
// Epilogue: combine K-halves + row-sums in LDS, normalize, leaky, coalesced out.
// ---------------------------------------------------------------------------
constexpr int BK  = 64;
constexpr int BKP = BK + 4;                    // 136B rows: 8B aligned, 2-way banks
constexpr int BL_BYTES   = 2 * Cn * BKP * 2;   // 69632
constexpr int QS_OFF     = BL_BYTES;           // 4KB qs
constexpr int COMB_W     = 257;
constexpr int COMB_BYTES = 128 * COMB_W * 4;   // 131584
constexpr int SH_OFF     = COMB_BYTES;         // Sh[8][32] f32
constexpr int SINV_OFF   = SH_OFF + 8 * 32 * 4;
constexpr int SMEM_BYTES = SINV_OFF + 128 * 4; // 133120

__global__ __launch_bounds__(512, 2) void ctx_kernel(
    const float* __restrict__ h,
    const float* __restrict__ pa_g, const float* __restrict__ q_g,
    float* __restrict__ out)
{
    __shared__ alignas(16) unsigned char smem[SMEM_BYTES];
    __bf16 (*Bl)[Cn][BKP] = (__bf16(*)[Cn][BKP])smem;
    float* qs             = (float*)(smem + QS_OFF);
    float (*comb)[COMB_W] = (float(*)[COMB_W])smem;
    float (*Sh)[32]       = (float(*)[32])(smem + SH_OFF);
    float* Sinv           = (float*)(smem + SINV_OFF);

    // XCD swizzle: 8 M-tile blocks of a batch share an XCD (h[b]=1MB, 4/XCD=4MB L2)
    int blk  = blockIdx.x;           // 256 blocks
    int xcd  = blk & 7;
    int slot = blk >> 3;             // 0..31
    int b    = xcd * 4 + (slot >> 3);
    int i0   = (slot & 7) * 128;

    int t    = threadIdx.x;
    int w    = t >> 6;               // wave 0..7
    int l    = t & 63;
    int half = w >> 2;               // K-half
    int wm   = w & 3;                // M-subtile (32 rows)
    int lm   = l & 31;
    int lh   = l >> 5;               // k-subhalf within MFMA

    const float* hb = h + (size_t)b * Cn * Nn;

    for (int i = t; i < Nn; i += 512) qs[i] = q_g[b * Nn + i];
    float pav = pa_g[b * Nn + i0 + wm * 32 + lm];

    v16f acc[8];
#pragma unroll
    for (int s = 0; s < 8; ++s)
#pragma unroll
        for (int r = 0; r < 16; ++r) acc[s][r] = 0.f;
    float Spart = 0.f;

    __syncthreads();                 // qs ready

    for (int tt = 0; tt < 8; ++tt) {
        __syncthreads();             // previous tile consumed
        // ---- stage both K-half tiles: h fp32 -> Bl[hh][c][k] bf16 ----
        // 8192 float4 chunks: chunk = t + 512*p
#pragma unroll
        for (int p = 0; p < 16; ++p) {
            int chunk = t + (p << 9);
            int hh    = chunk >> 12;
            int cc    = (chunk >> 4) & 255;
            int n4    = chunk & 15;
            int nbase = hh * 512 + tt * 64;
            float4 v  = *(const float4*)(hb + (size_t)cc * Nn + nbase + n4 * 4);
            union { __bf16 bx[4]; uint2 u; } pk;
            pk.bx[0] = (__bf16)v.x; pk.bx[1] = (__bf16)v.y;
            pk.bx[2] = (__bf16)v.z; pk.bx[3] = (__bf16)v.w;
            *(uint2*)&Bl[hh][cc][n4 * 4] = pk.u;
        }
        __syncthreads();

        int nt0 = half * 512 + tt * 64;
#pragma unroll
        for (int ks = 0; ks < 4; ++ks) {
            int n0 = nt0 + ks * 16;
            // ---- generate A-frag (E rows) in registers ----
            float4 q0 = *(const float4*)&qs[n0 + lh * 8];
            float4 q1 = *(const float4*)&qs[n0 + lh * 8 + 4];
            float qv[8] = {q0.x, q0.y, q0.z, q0.w, q1.x, q1.y, q1.z, q1.w};
            v8bf af;
#pragma unroll
            for (int j = 0; j < 8; ++j) {
                float z = pav * qv[j];                      // e^{2(a+k)}
                float r = __builtin_amdgcn_rcpf(1.f + z);
                float e = exp2f(fmaf(r, -2.f * K1, K1));    // e^{tanh}
                __bf16 eb = (__bf16)e;
                af[j] = eb;
                Spart += (float)eb;                         // bf16-consistent S
            }
            // ---- 8 c-subtiles of MFMA ----
#pragma unroll
            for (int s = 0; s < 8; ++s) {
                const __bf16* bp = &Bl[half][s * 32 + lm][ks * 16 + lh * 8];
                union { uint2 u2[2]; v8bf v; } bu;
                bu.u2[0] = *(const uint2*)bp;
                bu.u2[1] = *(const uint2*)(bp + 4);
                acc[s] = __builtin_amdgcn_mfma_f32_32x32x16_bf16(af, bu.v, acc[s], 0, 0, 0);
            }
        }
    }

    // ---- row sums: lanes l, l+32 hold same row's disjoint k-slices ----
    float So = Spart + __shfl_xor(Spart, 32);
    if (lh == 0) Sh[w][lm] = So;
    __syncthreads();

    // ---- K-half combine: waves 4-7 dump acc into comb ----
    if (w >= 4) {
#pragma unroll
        for (int s = 0; s < 8; ++s)
#pragma unroll
            for (int r = 0; r < 16; ++r) {
                int rl  = (r & 3) + 8 * (r >> 2) + 4 * lh;
                comb[wm * 32 + rl][s * 32 + lm] = acc[s][r];
            }
    }
    __syncthreads();
    if (t < 128) {
        float S = Sh[t >> 5][t & 31] + Sh[4 + (t >> 5)][t & 31];
        Sinv[t] = 1.f / S;
    }
    __syncthreads();
    // ---- waves 0-3: add halves, normalize, LeakyReLU, write back to comb ----
    if (w < 4) {
#pragma unroll
        for (int s = 0; s < 8; ++s)
#pragma unroll
            for (int r = 0; r < 16; ++r) {
                int rl  = (r & 3) + 8 * (r >> 2) + 4 * lh;
                int row = wm * 32 + rl;
                int col = s * 32 + lm;
                float v = (acc[s][r] + comb[row][col]) * Sinv[row];
                v = (v >= 0.f) ? v : 0.2f * v;
                comb[row][col] = v;
            }
    }
    __syncthreads();
    // ---- coalesced store: out[b][c][i0..i0+127] ----
    float* ob = out + (size_t)b * Cn * Nn + i0;
#pragma unroll
    for (int p = 0; p < 16; ++p) {
        int slot = t + (p << 9);      // 8192 float4 slots
        int c    = slot >> 5;
        int i4   = (slot & 31) * 4;
        float4 o;
        o.x = comb[i4 + 0][c];
        o.y = comb[i4 + 1][c];
        o.z = comb[i4 + 2][c];
        o.w = comb[i4 + 3][c];
        *(float4*)(ob + (size_t)c * Nn + i4) = o;
    }
}

// ---------------------------------------------------------------------------
extern "C" void kernel_launch(void* const* d_in, const int* in_sizes, int n_in,
                              void* d_out, int out_size, void* d_ws, size_t ws_size,
                              hipStream_t stream) {
    const float* h   = (const float*)d_in[0];
    const float* w1w = (const float*)d_in[1];
    const float* w1b = (const float*)d_in[2];
    const float* w2w = (const float*)d_in[3];
    const float* w2b = (const float*)d_in[4];
    float* out = (float*)d_out;

    float* pa_ws = (float*)d_ws;          // exp2(C2*a)
    float* q_ws  = pa_ws + Bn * Nn;       // exp2(C2*k)

    proj_kernel<<<Bn * 16, 256, 0, stream>>>(h, w1w, w1b, w2w, w2b, pa_ws, q_ws);
    ctx_kernel<<<Bn * 8, 512, 0, stream>>>(h, pa_ws, q_ws, out);
}

// Round 3
// 123.054 us; speedup vs baseline: 3.6110x; 1.2848x over previous
//
#include <hip/hip_runtime.h>

constexpr int Bn = 32;
constexpr int Cn = 256;
constexpr int Nn = 1024;

constexpr float C2 = 2.8853900817779268f;  // 2/ln2
constexpr float K1 = 1.4426950408889634f;  // 1/ln2

typedef __bf16 v8bf  __attribute__((ext_vector_type(8)));
typedef float  v16f  __attribute__((ext_vector_type(16)));

// hbf layout: [b][nt32][c][ni32] bf16, 16B groups XOR-swizzled: group g stored
// at (g ^ (c&3)). Row = 64B. b-stride 524288 B, nt-stride 16384 B, c-stride 64 B.

__device__ __forceinline__ void async16(const void* g, void* l) {
    __builtin_amdgcn_global_load_lds(
        (const __attribute__((address_space(1))) unsigned int*)g,
        (__attribute__((address_space(3))) unsigned int*)l, 16, 0, 0);
}

// ---------------------------------------------------------------------------
// Prep: dots a,k  ->  pa=e^{2a}, q=e^{2k};  h fp32 -> hbf bf16 (blocked+swizzled)
// grid 512: (xcd-swizzled b, 64-n chunk); 256 thr, wave = c-quarter, lane = n.
// ---------------------------------------------------------------------------
__global__ __launch_bounds__(256) void prep_kernel(
    const float* __restrict__ h,
    const float* __restrict__ w1, const float* __restrict__ w1b,
    const float* __restrict__ w2, const float* __restrict__ w2b,
    float* __restrict__ pa_g, float* __restrict__ q_g,
    unsigned char* __restrict__ hbf)
{
    int blk = blockIdx.x;
    int xcd = blk & 7, idx = blk >> 3;
    int b   = xcd * 4 + (idx >> 4);
    int n0  = (idx & 15) * 64;
    int t = threadIdx.x, cq = t >> 6, l = t & 63;

    const float* hb = h + (size_t)b * Cn * Nn + n0 + l;
    int nt32 = (n0 >> 5) + (l >> 5);
    unsigned char* wb = hbf + ((size_t)(b * 32 + nt32)) * 16384 + ((l & 7) << 1);
    int g = (l >> 3) & 3;

    float s1 = 0.f, s2 = 0.f;
#pragma unroll 8
    for (int ci = 0; ci < 64; ++ci) {
        int c = cq * 64 + ci;
        float v = hb[(size_t)c * Nn];
        s1 = fmaf(v, w1[c], s1);
        s2 = fmaf(v, w2[c], s2);
        union { __bf16 bv; unsigned short us; } u;
        u.bv = (__bf16)v;
        *(unsigned short*)(wb + c * 64 + ((g ^ (c & 3)) << 4)) = u.us;
    }
    __shared__ float p1[4][64], p2[4][64];
    p1[cq][l] = s1;
    p2[cq][l] = s2;
    __syncthreads();
    if (t < 64) {
        float a = p1[0][t] + p1[1][t] + p1[2][t] + p1[3][t] + w1b[0];
        float k = p2[0][t] + p2[1][t] + p2[2][t] + p2[3][t] + w2b[0];
        pa_g[b * Nn + n0 + t] = exp2f(C2 * a);
        q_g [b * Nn + n0 + t] = exp2f(C2 * k);
    }
}

// ---------------------------------------------------------------------------
// Ctx: block = (b, 64-row i-tile); 512 thr = 8 waves = (cq 0..3) x (wq K-half).
// Per 32-n tile: async-DMA B tiles (both halves) into LDS while generating
// E[64][64] (both halves) into LDS; then 8 MFMA per wave off swizzled b128.
// acc = 2x2 v16f (64 AGPR) -> 4 waves/SIMD, 2 blocks/CU.
// ---------------------------------------------------------------------------
constexpr int EST_OFF  = 32768;           // Bl [2][16384) at 0
constexpr int QS_OFF   = 65792;           // comb[64][257] f32 aliases [0,65792)
constexpr int SP_OFF   = 69888;
constexpr int SINV_OFF = 71936;
constexpr int CTX_SMEM = 72192;

__global__ __launch_bounds__(512, 4) void ctx_kernel(
    const unsigned char* __restrict__ hbf,
    const float* __restrict__ pa_g, const float* __restrict__ q_g,
    float* __restrict__ out)
{
    __shared__ alignas(16) unsigned char smem[CTX_SMEM];
    float* qs           = (float*)(smem + QS_OFF);
    float (*Sp)[64]     = (float(*)[64])(smem + SP_OFF);
    float* Sinv         = (float*)(smem + SINV_OFF);
    float (*comb)[257]  = (float(*)[257])smem;

    int blk = blockIdx.x;
    int xcd = blk & 7, slot = blk >> 3;
    int b   = xcd * 4 + (slot >> 4);
    int i0  = (slot & 15) * 64;

    int t = threadIdx.x, w = t >> 6, l = t & 63;
    int lm = l & 31, lh = l >> 5;
    int cq = w & 3, wq = w >> 2;

    const unsigned char* hbf_b = hbf + (size_t)b * 524288;

    for (int i = t; i < Nn; i += 512) qs[i] = q_g[b * Nn + i];
    float pav = pa_g[b * Nn + i0 + l];          // gen row = l

    v16f acc[2][2];
#pragma unroll
    for (int x = 0; x < 2; ++x)
#pragma unroll
        for (int y = 0; y < 2; ++y)
#pragma unroll
            for (int r = 0; r < 16; ++r) acc[x][y][r] = 0.f;
    float Spart = 0.f;

    unsigned char* estw = smem + EST_OFF + l * 128 + ((w ^ (l & 7)) << 4);

    for (int tt = 0; tt < 16; ++tt) {
        __syncthreads();                         // prev tile consumed (covers qs on tt=0)
        // ---- async stage B: both K-half 16KB slices, lane-linear ----
#pragma unroll
        for (int p = 0; p < 4; ++p) {
            int id = p * 8 + w;
            int hh = id >> 4, off = (id & 15) << 10;
            const unsigned char* src = hbf_b + (((hh << 4) + tt) << 14) + off + (l << 4);
            async16(src, smem + (hh << 14) + off);
        }
        // ---- generate E (overlaps DMA): wave w -> half w>>2, oct w&3 ----
        {
            int qb = (w >> 2) * 512 + tt * 32 + (w & 3) * 8;
            float4 q0 = *(const float4*)&qs[qb];
            float4 q1 = *(const float4*)&qs[qb + 4];
            float qv[8] = {q0.x, q0.y, q0.z, q0.w, q1.x, q1.y, q1.z, q1.w};
            v8bf ev;
#pragma unroll
            for (int j = 0; j < 8; ++j) {
                float z = pav * qv[j];                       // e^{2(a+k)}
                float r = __builtin_amdgcn_rcpf(1.f + z);
                float e = exp2f(fmaf(r, -2.f * K1, K1));     // e^{tanh}
                __bf16 eb = (__bf16)e;
                ev[j] = eb;
                Spart += (float)eb;
            }
            *(v8bf*)estw = ev;
        }
        __syncthreads();                         // DMA drained + Est ready
        // ---- MFMA phase: 8 b128 reads, 8 MFMA per wave ----
#pragma unroll
        for (int ks = 0; ks < 2; ++ks) {
            int gA = ((wq << 2) + (ks << 1) + lh) ^ (lm & 7);
            v8bf a0 = *(const v8bf*)(smem + EST_OFF + lm * 128        + (gA << 4));
            v8bf a1 = *(const v8bf*)(smem + EST_OFF + (32 + lm) * 128 + (gA << 4));
            int gB = ((ks << 1) + lh) ^ (lm & 3);
            const unsigned char* bB = smem + (wq << 14) + (cq * 64 + lm) * 64;
            v8bf b0 = *(const v8bf*)(bB +        (gB << 4));
            v8bf b1 = *(const v8bf*)(bB + 2048 + (gB << 4));   // +32 c rows
            acc[0][0] = __builtin_amdgcn_mfma_f32_32x32x16_bf16(a0, b0, acc[0][0], 0, 0, 0);
            acc[0][1] = __builtin_amdgcn_mfma_f32_32x32x16_bf16(a0, b1, acc[0][1], 0, 0, 0);
            acc[1][0] = __builtin_amdgcn_mfma_f32_32x32x16_bf16(a1, b0, acc[1][0], 0, 0, 0);
            acc[1][1] = __builtin_amdgcn_mfma_f32_32x32x16_bf16(a1, b1, acc[1][1], 0, 0, 0);
        }
    }

    // ---- epilogue ----
    Sp[w][l] = Spart;
    __syncthreads();                             // also: Bl/Est dead -> comb alias safe
    if (t < 64) {
        float S = 0.f;
#pragma unroll
        for (int ww = 0; ww < 8; ++ww) S += Sp[ww][t];
        Sinv[t] = 1.f / S;
    }
    if (wq == 1) {
#pragma unroll
        for (int x = 0; x < 2; ++x)
#pragma unroll
            for (int y = 0; y < 2; ++y)
#pragma unroll
                for (int r = 0; r < 16; ++r) {
                    int rl = (r & 3) + 8 * (r >> 2) + 4 * lh;
                    comb[x * 32 + rl][cq * 64 + y * 32 + lm] = acc[x][y][r];
                }
    }
    __syncthreads();
    if (wq == 0) {
#pragma unroll
        for (int x = 0; x < 2; ++x)
#pragma unroll
            for (int y = 0; y < 2; ++y)
#pragma unroll
                for (int r = 0; r < 16; ++r) {
                    int rl  = (r & 3) + 8 * (r >> 2) + 4 * lh;
                    int row = x * 32 + rl;
                    int col = cq * 64 + y * 32 + lm;
                    float v = (acc[x][y][r] + comb[row][col]) * Sinv[row];
                    v = (v >= 0.f) ? v : 0.2f * v;
                    comb[row][col] = v;
                }
    }
    __syncthreads();
    // ---- coalesced store out[b][c][i0..i0+63] ----
    float* ob = out + (size_t)b * Cn * Nn + i0;
#pragma unroll
    for (int p = 0; p < 8; ++p) {
        int slot = t + (p << 9);
        int c    = slot >> 4;
        int i4   = (slot & 15) << 2;
        float4 o;
        o.x = comb[i4 + 0][c];
        o.y = comb[i4 + 1][c];
        o.z = comb[i4 + 2][c];
        o.w = comb[i4 + 3][c];
        *(float4*)(ob + (size_t)c * Nn + i4) = o;
    }
}

// ---------------------------------------------------------------------------
extern "C" void kernel_launch(void* const* d_in, const int* in_sizes, int n_in,
                              void* d_out, int out_size, void* d_ws, size_t ws_size,
                              hipStream_t stream) {
    const float* h   = (const float*)d_in[0];
    const float* w1w = (const float*)d_in[1];
    const float* w1b = (const float*)d_in[2];
    const float* w2w = (const float*)d_in[3];
    const float* w2b = (const float*)d_in[4];
    float* out = (float*)d_out;

    float* pa_ws = (float*)d_ws;                              // [0, 128K)
    float* q_ws  = pa_ws + Bn * Nn;                           // [128K, 256K)
    unsigned char* hbf = (unsigned char*)d_ws + 262144;       // 16 MB blocked bf16

    prep_kernel<<<512, 256, 0, stream>>>(h, w1w, w1b, w2w, w2b, pa_ws, q_ws, hbf);
    ctx_kernel <<<512, 512, 0, stream>>>(hbf, pa_ws, q_ws, out);
}